// Round 9
// baseline (298.110 us; speedup 1.0000x reference)
//
#include <hip/hip_runtime.h>
#include <math.h>

typedef __attribute__((ext_vector_type(8))) short short8;
typedef __attribute__((ext_vector_type(4))) float float4v;

#define NS 48
#define PS 52
#define NC 64

// padded bf16 input: [n][xx 0..51][yy 0..51][zz 0..51][i], borders zero
__device__ __align__(16) unsigned short g_xb[(size_t)2 * PS * PS * PS * NC];
// kernel in MFMA B-fragment layout: [tap 125][ik 2][of 4][lane 64][j 8]
__device__ __align__(16) unsigned short g_kb[125 * 2 * 4 * 64 * 8];

__device__ __forceinline__ unsigned short bf16r(float f) {
  unsigned u = __builtin_bit_cast(unsigned, f);
  u = (u + 0x7FFFu + ((u >> 16) & 1u)) >> 16;
  return (unsigned short)u;
}

__global__ __launch_bounds__(256) void pad_cast(const float* __restrict__ x) {
  const int bx = blockIdx.x;  // xx*52+yy
  const int n = blockIdx.y;
  const int xx = bx / 52, yy = bx % 52;
  const bool inxy = (xx >= 2) && (xx < 50) && (yy >= 2) && (yy < 50);
  unsigned short* dst = g_xb + (((size_t)n * 52 + xx) * 52 + yy) * 3328;
  const float* src = x + ((((size_t)n * 48 + (xx - 2)) * 48 + (yy - 2)) * 48) * 64;
#pragma unroll 1
  for (int tt = threadIdx.x; tt < 832; tt += 256) {
    const int zz = tt >> 4;
    const int i4 = (tt & 15) * 4;
    ushort4 v = make_ushort4(0, 0, 0, 0);
    if (inxy && zz >= 2 && zz < 50) {
      const float4 f = *(const float4*)(src + (size_t)(zz - 2) * 64 + i4);
      v.x = bf16r(f.x); v.y = bf16r(f.y); v.z = bf16r(f.z); v.w = bf16r(f.w);
    }
    *(ushort4*)(dst + (size_t)zz * 64 + i4) = v;
  }
}

__global__ __launch_bounds__(256) void build_kb(
    const float* __restrict__ w000, const float* __restrict__ w011,
    const float* __restrict__ w101, const float* __restrict__ w110,
    const float* __restrict__ sc0,  const float* __restrict__ sc1) {
  const int tap = blockIdx.x;  // 0..124
  const int tz = tap % 5, ty = (tap / 5) % 5, tx = tap / 25;
  const float cx = (float)(tx - 2), cy = (float)(ty - 2), cz = (float)(tz - 2);
  const float norm = sqrtf(cx * cx + cy * cy + cz * cz);
  const float inv = (norm > 0.f) ? (1.f / norm) : 0.f;
  const float SQ3 = 1.7320508075688772f;
  const float sh[3] = {SQ3 * cx * inv, SQ3 * cy * inv, SQ3 * cz * inv};
  float emb[4];
#pragma unroll
  for (int b = 0; b < 4; ++b) {
    const float v = 0.5f * (float)(b + 1);
    const float d = (norm - v) * 2.0f;
    emb[b] = (fabsf(d) < 1.f) ? 1.14136f * expf(2.f - 1.f / (1.f - d * d)) : 0.f;
  }
  const bool center = (tap == 62);
  const float INV_NLAT = 1.0f / 125.0f;
  const float INV_SQ3 = 0.57735026918962576f;
  for (int e = threadIdx.x; e < 4096; e += blockDim.x) {
    const int r = e >> 6, c = e & 63;  // r = input ch, c = output ch
    float val = 0.f;
    if (center) {
      if (r < 16 && c < 16) {
        val = sc0[r * 16 + c] * 0.25f;
      } else if (r >= 16 && c >= 16) {
        const int u = (r - 16) / 3, i = (r - 16) % 3;
        const int w = (c - 16) / 3, kc = (c - 16) % 3;
        val = (i == kc) ? sc1[u * 16 + w] * 0.25f : 0.f;
      }
    } else {
      if (r < 16 && c < 16) {
        float a = 0.f;
#pragma unroll
        for (int b = 0; b < 4; ++b) a += emb[b] * w000[(b * 16 + r) * 16 + c];
        val = a * INV_NLAT;
      } else if (r < 16) {
        const int w = (c - 16) / 3, kc = (c - 16) % 3;
        float a = 0.f;
#pragma unroll
        for (int b = 0; b < 4; ++b) a += emb[b] * w011[(b * 16 + r) * 16 + w];
        val = a * INV_NLAT * sh[kc];
      } else if (c < 16) {
        const int u = (r - 16) / 3, i = (r - 16) % 3;
        float a = 0.f;
#pragma unroll
        for (int b = 0; b < 4; ++b) a += emb[b] * w110[(b * 16 + u) * 16 + c];
        val = a * INV_NLAT * sh[i] * INV_SQ3;
      } else {
        const int u = (r - 16) / 3, i = (r - 16) % 3;
        const int w = (c - 16) / 3, kc = (c - 16) % 3;
        if (i == kc) {
          float a = 0.f;
#pragma unroll
          for (int b = 0; b < 4; ++b) a += emb[b] * w101[(b * 16 + u) * 16 + w];
          val = a * INV_NLAT;
        }
      }
    }
    // permute into B-fragment layout: B[k = i - ik*32][n = o] per (tap, ik, of)
    const int ik = r >> 5;
    const int lane = ((r >> 3) & 3) * 16 + (c & 15);
    const int of = c >> 4;
    const int j = r & 7;
    g_kb[((size_t)((tap * 2 + ik) * 4 + of) * 64 + lane) * 8 + j] = bf16r(val);
  }
}

// ONE-WAVE workgroup: 2y x 48z x 64o per block. No barriers — wave-private
// slab 6y-halo x 52z x 32ch = 19968 B, XOR-swizzled (ry>>1)&3; ordering via
// s_waitcnt only. 8 blocks/CU by LDS, all independently pipelined.
__global__ __launch_bounds__(64, 2) void conv_mfma(float* __restrict__ out) {
  __shared__ __align__(16) char xs[6 * 52 * 64];  // 19968 B
  const int l = threadIdx.x;   // 0..63
  const int m = l & 15;        // z-within-tile (A) / o-within-frag (C)
  const int kq = l >> 4;       // k-quad 0..3
  // bijective XCD swizzle: 2304 blocks = 8 XCDs x 288, X fastest
  const int bid = blockIdx.x;
  const int wg = (bid & 7) * 288 + (bid >> 3);
  const int X = wg % 48;
  const int yg = (wg / 48) % 24;
  const int n = wg / 1152;
  const int y0 = yg << 1;      // output rows y0, y0+1

  float4v acc[2][3][4];
  const float4v zero4 = {0.f, 0.f, 0.f, 0.f};
#pragma unroll
  for (int y = 0; y < 2; ++y)
#pragma unroll
    for (int zt = 0; zt < 3; ++zt)
#pragma unroll
      for (int of = 0; of < 4; ++of) acc[y][zt][of] = zero4;

  // compute one tap group g (= dy*5+dz) with the given B register set
  auto compute = [&](int g, const short8& b0, const short8& b1,
                     const short8& b2, const short8& b3) {
    const int dy = g / 5, dz = g % 5;
#pragma unroll
    for (int y = 0; y < 2; ++y) {
#pragma unroll
      for (int zt = 0; zt < 3; ++zt) {
        const int ry = (dy + y) * 52 + m + dz + zt * 16;
        const int byte = ry * 64 + ((kq ^ ((ry >> 1) & 3)) << 4);
        const short8 a = *(const short8*)(xs + byte);
        acc[y][zt][0] = __builtin_amdgcn_mfma_f32_16x16x32_bf16(a, b0, acc[y][zt][0], 0, 0, 0);
        acc[y][zt][1] = __builtin_amdgcn_mfma_f32_16x16x32_bf16(a, b1, acc[y][zt][1], 0, 0, 0);
        acc[y][zt][2] = __builtin_amdgcn_mfma_f32_16x16x32_bf16(a, b2, acc[y][zt][2], 0, 0, 0);
        acc[y][zt][3] = __builtin_amdgcn_mfma_f32_16x16x32_bf16(a, b3, acc[y][zt][3], 0, 0, 0);
      }
    }
  };

#pragma unroll 1
  for (int ph = 0; ph < 10; ++ph) {
    const int dx = ph >> 1, h = ph & 1;
    // all ds_reads of the previous phase already have MFMA consumers behind
    // lgkmcnt waits; make re-staging provably safe, then stage.
    asm volatile("s_waitcnt lgkmcnt(0)" ::: "memory");
    {
      // stage 6y x 52z x 32ch slab: 1248 16B-chunks = 19.5/lane; linear LDS
      // dest, source pre-swizzled (chunk ^= (ry>>1)&3) to match read side.
      const unsigned short* gx =
          g_xb + ((size_t)n * PS + (X + dx)) * 173056 + (size_t)y0 * 3328;
#pragma unroll
      for (int s = 0; s < 20; ++s) {
        const int cl = l + (s << 6);
        if (cl < 1248) {
          const int ry = cl >> 2, p = cl & 3;
          const int jy = ry / 52, zz = ry - jy * 52;
          const int sc = p ^ ((ry >> 1) & 3);
          const unsigned short* g = gx + jy * 3328 + zz * 64 + h * 32 + sc * 8;
          char* ldsd = xs + (size_t)(s << 10);  // wave-uniform base + lane*16
          __builtin_amdgcn_global_load_lds(
              (const __attribute__((address_space(1))) unsigned*)g,
              (__attribute__((address_space(3))) unsigned*)ldsd, 16, 0, 0);
        }
      }
    }
    asm volatile("s_waitcnt vmcnt(0)" ::: "memory");
    __builtin_amdgcn_sched_barrier(0);

    // B base for this phase: kb index = ((dx*25 + g)*2 + h)*2048
    const unsigned short* kb0 = g_kb + (size_t)(dx * 50 + h) * 2048 + l * 8;
    auto loadB = [&](int g, short8& b0, short8& b1, short8& b2, short8& b3) {
      const unsigned short* kbp = kb0 + (size_t)g * 4096;
      b0 = *(const short8*)(kbp);
      b1 = *(const short8*)(kbp + 512);
      b2 = *(const short8*)(kbp + 1024);
      b3 = *(const short8*)(kbp + 1536);
    };

    short8 bA0, bA1, bA2, bA3, bB0, bB1, bB2, bB3;
    loadB(0, bA0, bA1, bA2, bA3);
#pragma unroll 1
    for (int gg = 0; gg < 12; ++gg) {
      const int g0 = gg * 2;
      loadB(g0 + 1, bB0, bB1, bB2, bB3);   // prefetch next
      compute(g0, bA0, bA1, bA2, bA3);     // 24 MFMA hide the load
      loadB(g0 + 2, bA0, bA1, bA2, bA3);   // prefetch next+1
      compute(g0 + 1, bB0, bB1, bB2, bB3);
    }
    compute(24, bA0, bA1, bA2, bA3);
  }

  // C/D layout: col(o) = lane&15, row(z) = (lane>>4)*4 + r   [m89]
#pragma unroll
  for (int y = 0; y < 2; ++y) {
    float* op = out + ((((size_t)n * NS + X) * NS + (y0 + y)) * NS) * NC;
#pragma unroll
    for (int zt = 0; zt < 3; ++zt) {
#pragma unroll
      for (int of = 0; of < 4; ++of) {
#pragma unroll
        for (int r = 0; r < 4; ++r) {
          const int z = zt * 16 + kq * 4 + r;
          const int o = of * 16 + m;
          op[(size_t)z * NC + o] = acc[y][zt][of][r];
        }
      }
    }
  }
}

extern "C" void kernel_launch(void* const* d_in, const int* in_sizes, int n_in,
                              void* d_out, int out_size, void* d_ws, size_t ws_size,
                              hipStream_t stream) {
  const float* x    = (const float*)d_in[0];
  const float* w000 = (const float*)d_in[1];
  const float* w011 = (const float*)d_in[2];
  const float* w101 = (const float*)d_in[3];
  const float* w110 = (const float*)d_in[4];
  const float* sc0  = (const float*)d_in[5];
  const float* sc1  = (const float*)d_in[6];
  float* out = (float*)d_out;

  pad_cast<<<dim3(52 * 52, 2), 256, 0, stream>>>(x);
  build_kb<<<125, 256, 0, stream>>>(w000, w011, w101, w110, sc0, sc1);
  conv_mfma<<<2304, 64, 0, stream>>>(out);
}

// Round 11
// 265.429 us; speedup vs baseline: 1.1231x; 1.1231x over previous
//
#include <hip/hip_runtime.h>
#include <math.h>

typedef __attribute__((ext_vector_type(8))) short short8;
typedef __attribute__((ext_vector_type(4))) float float4v;

#define NS 48
#define PS 52
#define NC 64

// padded bf16 input: [n][xx 0..51][yy 0..51][zz 0..51][i], borders zero
__device__ __align__(16) unsigned short g_xb[(size_t)2 * PS * PS * PS * NC];
// kernel in MFMA B-fragment layout: [tap 125][ik 2][of 4][lane 64][j 8]
__device__ __align__(16) unsigned short g_kb[125 * 2 * 4 * 64 * 8];

__device__ __forceinline__ unsigned short bf16r(float f) {
  unsigned u = __builtin_bit_cast(unsigned, f);
  u = (u + 0x7FFFu + ((u >> 16) & 1u)) >> 16;
  return (unsigned short)u;
}

__global__ __launch_bounds__(256) void pad_cast(const float* __restrict__ x) {
  const int bx = blockIdx.x;  // xx*52+yy
  const int n = blockIdx.y;
  const int xx = bx / 52, yy = bx % 52;
  const bool inxy = (xx >= 2) && (xx < 50) && (yy >= 2) && (yy < 50);
  unsigned short* dst = g_xb + (((size_t)n * 52 + xx) * 52 + yy) * 3328;
  const float* src = x + ((((size_t)n * 48 + (xx - 2)) * 48 + (yy - 2)) * 48) * 64;
#pragma unroll 1
  for (int tt = threadIdx.x; tt < 832; tt += 256) {
    const int zz = tt >> 4;
    const int i4 = (tt & 15) * 4;
    ushort4 v = make_ushort4(0, 0, 0, 0);
    if (inxy && zz >= 2 && zz < 50) {
      const float4 f = *(const float4*)(src + (size_t)(zz - 2) * 64 + i4);
      v.x = bf16r(f.x); v.y = bf16r(f.y); v.z = bf16r(f.z); v.w = bf16r(f.w);
    }
    *(ushort4*)(dst + (size_t)zz * 64 + i4) = v;
  }
}

__global__ __launch_bounds__(256) void build_kb(
    const float* __restrict__ w000, const float* __restrict__ w011,
    const float* __restrict__ w101, const float* __restrict__ w110,
    const float* __restrict__ sc0,  const float* __restrict__ sc1) {
  const int tap = blockIdx.x;  // 0..124
  const int tz = tap % 5, ty = (tap / 5) % 5, tx = tap / 25;
  const float cx = (float)(tx - 2), cy = (float)(ty - 2), cz = (float)(tz - 2);
  const float norm = sqrtf(cx * cx + cy * cy + cz * cz);
  const float inv = (norm > 0.f) ? (1.f / norm) : 0.f;
  const float SQ3 = 1.7320508075688772f;
  const float sh[3] = {SQ3 * cx * inv, SQ3 * cy * inv, SQ3 * cz * inv};
  float emb[4];
#pragma unroll
  for (int b = 0; b < 4; ++b) {
    const float v = 0.5f * (float)(b + 1);
    const float d = (norm - v) * 2.0f;
    emb[b] = (fabsf(d) < 1.f) ? 1.14136f * expf(2.f - 1.f / (1.f - d * d)) : 0.f;
  }
  const bool center = (tap == 62);
  const float INV_NLAT = 1.0f / 125.0f;
  const float INV_SQ3 = 0.57735026918962576f;
  for (int e = threadIdx.x; e < 4096; e += blockDim.x) {
    const int r = e >> 6, c = e & 63;  // r = input ch, c = output ch
    float val = 0.f;
    if (center) {
      if (r < 16 && c < 16) {
        val = sc0[r * 16 + c] * 0.25f;
      } else if (r >= 16 && c >= 16) {
        const int u = (r - 16) / 3, i = (r - 16) % 3;
        const int w = (c - 16) / 3, kc = (c - 16) % 3;
        val = (i == kc) ? sc1[u * 16 + w] * 0.25f : 0.f;
      }
    } else {
      if (r < 16 && c < 16) {
        float a = 0.f;
#pragma unroll
        for (int b = 0; b < 4; ++b) a += emb[b] * w000[(b * 16 + r) * 16 + c];
        val = a * INV_NLAT;
      } else if (r < 16) {
        const int w = (c - 16) / 3, kc = (c - 16) % 3;
        float a = 0.f;
#pragma unroll
        for (int b = 0; b < 4; ++b) a += emb[b] * w011[(b * 16 + r) * 16 + w];
        val = a * INV_NLAT * sh[kc];
      } else if (c < 16) {
        const int u = (r - 16) / 3, i = (r - 16) % 3;
        float a = 0.f;
#pragma unroll
        for (int b = 0; b < 4; ++b) a += emb[b] * w110[(b * 16 + u) * 16 + c];
        val = a * INV_NLAT * sh[i] * INV_SQ3;
      } else {
        const int u = (r - 16) / 3, i = (r - 16) % 3;
        const int w = (c - 16) / 3, kc = (c - 16) % 3;
        if (i == kc) {
          float a = 0.f;
#pragma unroll
          for (int b = 0; b < 4; ++b) a += emb[b] * w101[(b * 16 + u) * 16 + w];
          val = a * INV_NLAT;
        }
      }
    }
    // permute into B-fragment layout: B[k = i - ik*32][n = o] per (tap, ik, of)
    const int ik = r >> 5;
    const int lane = ((r >> 3) & 3) * 16 + (c & 15);
    const int of = c >> 4;
    const int j = r & 7;
    g_kb[((size_t)((tap * 2 + ik) * 4 + of) * 64 + lane) * 8 + j] = bf16r(val);
  }
}

// Block: 6y x 48z x 64o, 3 waves (192 thr). Wave w owns y rows {y0+2w, y0+2w+1}.
// Slab: 10y-halo x 52z x 32ch = 33280 B, XOR-swizzled (ry>>1)&3.
// Grid 768 = 8 XCDs x 96 = EXACTLY 3 blocks/CU: zero tail, zero imbalance.
__global__ __launch_bounds__(192, 3) void conv_mfma(float* __restrict__ out) {
  __shared__ __align__(16) char xs[10 * 52 * 64];  // 33280 B
  const int t = threadIdx.x;
  const int l = t & 63;
  const int wid = t >> 6;      // 0..2
  const int m = l & 15;        // z-within-tile (A) / o-within-frag (C)
  const int kq = l >> 4;       // k-quad 0..3
  // bijective XCD swizzle: 768 blocks = 8 XCDs x 96, X fastest
  const int bid = blockIdx.x;
  const int wg = (bid & 7) * 96 + (bid >> 3);
  const int X = wg % 48;
  const int r16 = wg / 48;     // 0..15
  const int yg = r16 & 7;
  const int n = r16 >> 3;
  const int y0 = yg * 6;

  float4v acc[2][3][4];
  const float4v zero4 = {0.f, 0.f, 0.f, 0.f};
#pragma unroll
  for (int y = 0; y < 2; ++y)
#pragma unroll
    for (int zt = 0; zt < 3; ++zt)
#pragma unroll
      for (int of = 0; of < 4; ++of) acc[y][zt][of] = zero4;

#pragma unroll 1
  for (int ph = 0; ph < 10; ++ph) {
    const int dx = ph >> 1, h = ph & 1;
    __syncthreads();
    {
      // stage 10y x 52z x 32ch half-slab: 2080 16B-chunks, linear LDS dest,
      // source pre-swizzled (chunk ^= (ry>>1)&3) to match swizzled read.
      const unsigned short* gx =
          g_xb + ((size_t)n * PS + (X + dx)) * 173056 + (size_t)y0 * 3328;
#pragma unroll
      for (int s = 0; s < 11; ++s) {
        const int cl = t + s * 192;
        if (cl < 2080) {
          const int ry = cl >> 2, p = cl & 3;
          const int jy = ry / 52, zz = ry - jy * 52;
          const int sc = p ^ ((ry >> 1) & 3);
          const unsigned short* g = gx + jy * 3328 + zz * 64 + h * 32 + sc * 8;
          char* ldsd = xs + (size_t)((s * 192 + wid * 64) * 16);
          __builtin_amdgcn_global_load_lds(
              (const __attribute__((address_space(1))) unsigned*)g,
              (__attribute__((address_space(3))) unsigned*)ldsd, 16, 0, 0);
        }
      }
    }
    __syncthreads();

#pragma unroll 1
    for (int dy = 0; dy < 5; ++dy) {
      const int rbase = (2 * wid + dy) * 52 + m;     // slab row for y=0
      const int tapb = ((dx * 5 + dy) * 5) * 2 + h;  // (tap*2 + ik), ik=h
#pragma unroll
      for (int dz = 0; dz < 5; ++dz) {
        const unsigned short* kbp =
            g_kb + (size_t)(tapb + dz * 2) * 2048 + l * 8;
        const short8 b0 = *(const short8*)(kbp);
        const short8 b1 = *(const short8*)(kbp + 512);
        const short8 b2 = *(const short8*)(kbp + 1024);
        const short8 b3 = *(const short8*)(kbp + 1536);
        short8 a[2][3];
#pragma unroll
        for (int y = 0; y < 2; ++y) {
#pragma unroll
          for (int zt = 0; zt < 3; ++zt) {
            const int ry = rbase + y * 52 + zt * 16 + dz;
            const int byte = ry * 64 + ((kq ^ ((ry >> 1) & 3)) << 4);
            a[y][zt] = *(const short8*)(xs + byte);
          }
        }
#pragma unroll
        for (int y = 0; y < 2; ++y) {
#pragma unroll
          for (int zt = 0; zt < 3; ++zt) {
            acc[y][zt][0] = __builtin_amdgcn_mfma_f32_16x16x32_bf16(a[y][zt], b0, acc[y][zt][0], 0, 0, 0);
            acc[y][zt][1] = __builtin_amdgcn_mfma_f32_16x16x32_bf16(a[y][zt], b1, acc[y][zt][1], 0, 0, 0);
            acc[y][zt][2] = __builtin_amdgcn_mfma_f32_16x16x32_bf16(a[y][zt], b2, acc[y][zt][2], 0, 0, 0);
            acc[y][zt][3] = __builtin_amdgcn_mfma_f32_16x16x32_bf16(a[y][zt], b3, acc[y][zt][3], 0, 0, 0);
          }
        }
      }
    }
  }

  // C/D layout: col(o) = lane&15, row(z) = (lane>>4)*4 + r   [m89]
#pragma unroll
  for (int y = 0; y < 2; ++y) {
    float* op = out +
        ((((size_t)n * NS + X) * NS + (y0 + 2 * wid + y)) * NS) * NC;
#pragma unroll
    for (int zt = 0; zt < 3; ++zt) {
#pragma unroll
      for (int of = 0; of < 4; ++of) {
#pragma unroll
        for (int r = 0; r < 4; ++r) {
          const int z = zt * 16 + kq * 4 + r;
          const int o = of * 16 + m;
          op[(size_t)z * NC + o] = acc[y][zt][of][r];
        }
      }
    }
  }
}

extern "C" void kernel_launch(void* const* d_in, const int* in_sizes, int n_in,
                              void* d_out, int out_size, void* d_ws, size_t ws_size,
                              hipStream_t stream) {
  const float* x    = (const float*)d_in[0];
  const float* w000 = (const float*)d_in[1];
  const float* w011 = (const float*)d_in[2];
  const float* w101 = (const float*)d_in[3];
  const float* w110 = (const float*)d_in[4];
  const float* sc0  = (const float*)d_in[5];
  const float* sc1  = (const float*)d_in[6];
  float* out = (float*)d_out;

  pad_cast<<<dim3(52 * 52, 2), 256, 0, stream>>>(x);
  build_kb<<<125, 256, 0, stream>>>(w000, w011, w101, w110, sc0, sc1);
  conv_mfma<<<768, 192, 0, stream>>>(out);
}